// Round 1
// baseline (115.709 us; speedup 1.0000x reference)
//
#include <hip/hip_runtime.h>

// HilbertSchmidtVQ — straight-through estimator forward pass.
//
// reference: out = rho_flat + (quantized - stop_gradient(quantized))
// In value arithmetic, quantized - quantized == 0 bitwise (same finite array
// subtracted from itself), so out == rho_flat EXACTLY. The argmin/gather over
// the codebook only affects gradients, which this single-output forward bench
// never evaluates. Hence the whole (N=65536, K=2048, DIM=256) distance
// computation is dead code for the value path.
//
// Optimal implementation: a 64 MiB fp32 D2D copy of rho_flat into d_out.
// hipMemcpyAsync(d2d, stream) is graph-capture-safe per harness rules and
// uses the driver's optimized copy path.

extern "C" void kernel_launch(void* const* d_in, const int* in_sizes, int n_in,
                              void* d_out, int out_size, void* d_ws, size_t ws_size,
                              hipStream_t stream) {
    const float* rho_flat = (const float*)d_in[0];   // (N, DIM) fp32
    float* out = (float*)d_out;                      // (N, DIM) fp32

    hipMemcpyAsync(out, rho_flat,
                   (size_t)out_size * sizeof(float),
                   hipMemcpyDeviceToDevice, stream);
}

// Round 2
// 111.666 us; speedup vs baseline: 1.0362x; 1.0362x over previous
//
#include <hip/hip_runtime.h>

// HilbertSchmidtVQ — straight-through estimator forward pass.
//
// reference: out = rho_flat + (quantized - stop_gradient(quantized))
// Forward value == rho_flat bitwise (quantized cancels itself exactly).
// The argmin/gather path only affects gradients, never evaluated here.
//
// R1 learning: hipMemcpyAsync D2D routes through SDMA/blit at ~1.16 TB/s
// (115.7 us). A float4 copy kernel reaches ~6.3 TB/s (m13), ~22 us.
//
// N*DIM = 16,777,216 floats = 4,194,304 float4 = 64 MiB.
// 16384 blocks x 256 threads x 16 B = exact cover, tail-guarded anyway.

__global__ __launch_bounds__(256) void copy_f4(const float4* __restrict__ src,
                                               float4* __restrict__ dst,
                                               int n4) {
    int i = blockIdx.x * blockDim.x + threadIdx.x;
    if (i < n4) dst[i] = src[i];
}

extern "C" void kernel_launch(void* const* d_in, const int* in_sizes, int n_in,
                              void* d_out, int out_size, void* d_ws, size_t ws_size,
                              hipStream_t stream) {
    const float4* rho = (const float4*)d_in[0];  // (N, DIM) fp32, 16B-aligned
    float4* out = (float4*)d_out;

    int n4 = out_size / 4;                       // out_size = 16,777,216 (mult of 4)
    int block = 256;
    int grid = (n4 + block - 1) / block;         // 16384
    copy_f4<<<grid, block, 0, stream>>>(rho, out, n4);
}